// Round 5
// baseline (18005.585 us; speedup 1.0000x reference)
//
#include <hip/hip_runtime.h>
#include <cstdint>
#include <cstddef>

typedef unsigned short u16;
typedef unsigned int u32;
typedef unsigned long long u64;
typedef __attribute__((ext_vector_type(8))) short bfrag8;   // 8 bf16 = 4 VGPRs
typedef __attribute__((ext_vector_type(4))) float f32x4;

#define NB 64      // batch
#define NT 512     // timesteps
#define NE 256     // embedding dim
#define NH 512     // hidden dim
#define NWG 128    // persistent workgroups (4 units x 4 gates = 16 cols each)
#define FS 16      // flag stride in ints (64 B apart)

__device__ __forceinline__ float bf2f(u16 b) { return __uint_as_float(((unsigned)b) << 16); }
__device__ __forceinline__ u16 f2bf(float f) {
  unsigned u = __float_as_uint(f);
  u += 0x7fffu + ((u >> 16) & 1u);   // round-to-nearest-even
  return (u16)(u >> 16);
}
__device__ __forceinline__ float fsigm(float x) { return 1.0f / (1.0f + __expf(-x)); }
__device__ __forceinline__ float ftanh(float x) { return 2.0f / (1.0f + __expf(-2.0f * x)) - 1.0f; }

// split fp32 -> (hi, lo) bf16 pair; hi + lo == v to ~2^-18 relative
__device__ __forceinline__ void split1(float v, u16& h, u16& l) {
  h = f2bf(v);
  float r = v - bf2f(h);
  l = f2bf(r);
}
__device__ __forceinline__ void split8(const float* p, bfrag8& hi, bfrag8& lo) {
#pragma unroll
  for (int i = 0; i < 8; ++i) {
    u16 h, l; split1(p[i], h, l);
    hi[i] = (short)h; lo[i] = (short)l;
  }
}

__device__ __forceinline__ void unpack8(uint4 q, float* o) {
  o[0] = __uint_as_float(q.x << 16); o[1] = __uint_as_float(q.x & 0xffff0000u);
  o[2] = __uint_as_float(q.y << 16); o[3] = __uint_as_float(q.y & 0xffff0000u);
  o[4] = __uint_as_float(q.z << 16); o[5] = __uint_as_float(q.z & 0xffff0000u);
  o[6] = __uint_as_float(q.w << 16); o[7] = __uint_as_float(q.w & 0xffff0000u);
}

// ---------------- persistent LSTM recurrence (fp32-accurate via split-bf16 MFMA) ----
// WG g owns hidden units [g*4, g*4+4) x 4 gates (16 output cols), all 64 batches.
// col c in [0,16): gate = c>>2 (0=r,1=f,2=g,3=o), unit = g*4 + (c&3).
// wave w handles batch tile [w*16, w*16+16).
// REGULAR launch (cooperative launch fails silently in this harness): 128 blocks
// <= 256 CUs, 1 block/CU even at 1-wave/SIMD occupancy -> all blocks co-resident,
// flag-based step sync cannot starve.
// COHERENCE (G16): h exchange crosses XCDs -> hbuf accessed ONLY via device-scope
// atomics (packed hi|lo<<16 u32); flags via device-scope atomics with acquire/release.
__global__ __launch_bounds__(256, 1) void lstm_persistent(
    const int* __restrict__ words,
    const float* __restrict__ emb,
    const float* __restrict__ Whr, const float* __restrict__ Whf,
    const float* __restrict__ Whg, const float* __restrict__ Who,
    const float* __restrict__ Wir, const float* __restrict__ Wif,
    const float* __restrict__ Wig, const float* __restrict__ Wio,
    const float* __restrict__ bhr, const float* __restrict__ bhf,
    const float* __restrict__ bhg, const float* __restrict__ bho,
    const float* __restrict__ bir, const float* __restrict__ bif,
    const float* __restrict__ big_, const float* __restrict__ bio,
    u32* __restrict__ hbuf,     // [2][B][H] packed bf16 hi | lo<<16
    u16* __restrict__ hs_all,   // [T][B][H] bf16 (attention path)
    float* __restrict__ hlast,  // [B][H] fp32 final h
    int* __restrict__ flags)    // [NWG*FS]
{
  const int wg = blockIdx.x;
  const int tid = threadIdx.x;
  const int lane = tid & 63;
  const int wave = tid >> 6;
  const int mbase = wave * 16;
  const int colq = lane & 15;
  const int koff = (lane >> 4) * 8;
  const int arow = mbase + colq;            // batch row for A fragments

  __shared__ float gatesLds[NB * 17];       // [b][col], stride 17
  __shared__ float biasSum[16];

  if (tid < 16) {
    int gate = tid >> 2, u = tid & 3, gu = wg * 4 + u;
    const float* bh = (gate == 0) ? bhr : (gate == 1) ? bhf : (gate == 2) ? bhg : bho;
    const float* bi = (gate == 0) ? bir : (gate == 1) ? bif : (gate == 2) ? big_ : bio;
    biasSum[tid] = bh[gu] + bi[gu];
  }

  // ---- persistent weight fragments (hi/lo split), B-layout:
  // lane L holds B[k=(L>>4)*8+j][col=L&15]
  bfrag8 whh[16], whl[16], wih[8], wil[8];
  {
    int gate = colq >> 2;
    int gu = wg * 4 + (colq & 3);
    const float* wh = (gate == 0) ? Whr : (gate == 1) ? Whf : (gate == 2) ? Whg : Who;
    const float* wi = (gate == 0) ? Wir : (gate == 1) ? Wif : (gate == 2) ? Wig : Wio;
    const float* whp = wh + (size_t)gu * NH + koff;
    const float* wip = wi + (size_t)gu * NE + koff;
#pragma unroll
    for (int kt = 0; kt < 16; ++kt) split8(whp + kt * 32, whh[kt], whl[kt]);
#pragma unroll
    for (int kt = 0; kt < 8; ++kt)  split8(wip + kt * 32, wih[kt], wil[kt]);
  }
  __syncthreads();

  // int64-vs-int32 hedge for word indices
  bool is64 = ((words[1] | words[3] | words[5] | words[7]) == 0);
  const int wstep = is64 ? 2 : 1;
  const int* wrow = words + (size_t)(is64 ? 2 : 1) * arow * NT;

  float cst = 0.0f;   // fp32 cell state for (b = tid>>2, u = tid&3)

  for (int t = 1; t <= NT; ++t) {
    // ---- issue embedding loads early (latency overlaps the flag poll) ----
    int w = wrow[(size_t)(t - 1) * wstep];
    const float* xsrc = emb + (size_t)w * NE + koff;
    f32x4 xa[8], xb[8];
#pragma unroll
    for (int kt = 0; kt < 8; ++kt) {
      xa[kt] = *(const f32x4*)(xsrc + kt * 32);
      xb[kt] = *(const f32x4*)(xsrc + kt * 32 + 4);
    }

    f32x4 acc = {0.f, 0.f, 0.f, 0.f};

    if (t > 1) {
      // ---- wait for all 128 WGs to publish h_{t-1} ----
      const int need = t - 1;
      int f0, f1;
      do {
        f0 = __hip_atomic_load(&flags[lane * FS], __ATOMIC_RELAXED, __HIP_MEMORY_SCOPE_AGENT);
        f1 = __hip_atomic_load(&flags[(lane + 64) * FS], __ATOMIC_RELAXED, __HIP_MEMORY_SCOPE_AGENT);
      } while (__all(f0 >= need && f1 >= need) == 0);
      // acquire ordering + cache invalidate before touching h data
      (void)__hip_atomic_load(&flags[wg * FS], __ATOMIC_ACQUIRE, __HIP_MEMORY_SCOPE_AGENT);
      __threadfence();

      // h loads: device-scope atomic u64 (coherent point; immune to stale per-XCD L2)
      const u64* hp = (const u64*)(hbuf + ((size_t)((t - 1) & 1) * NB + arow) * NH + koff);
#pragma unroll
      for (int kt = 0; kt < 16; ++kt) {
        bfrag8 ah, al;
#pragma unroll
        for (int jj = 0; jj < 4; ++jj) {
          u64 q = __hip_atomic_load((const u64*)(hp + kt * 16 + jj),
                                    __ATOMIC_RELAXED, __HIP_MEMORY_SCOPE_AGENT);
          u32 q0 = (u32)q, q1 = (u32)(q >> 32);
          ah[2 * jj]     = (short)(q0 & 0xffffu);
          al[2 * jj]     = (short)(q0 >> 16);
          ah[2 * jj + 1] = (short)(q1 & 0xffffu);
          al[2 * jj + 1] = (short)(q1 >> 16);
        }
        acc = __builtin_amdgcn_mfma_f32_16x16x32_bf16(ah, whh[kt], acc, 0, 0, 0);
        acc = __builtin_amdgcn_mfma_f32_16x16x32_bf16(al, whh[kt], acc, 0, 0, 0);
        acc = __builtin_amdgcn_mfma_f32_16x16x32_bf16(ah, whl[kt], acc, 0, 0, 0);
      }
    }

    // ---- input-projection part (fp32 emb split on the fly) ----
#pragma unroll
    for (int kt = 0; kt < 8; ++kt) {
      bfrag8 xh, xl;
#pragma unroll
      for (int i = 0; i < 4; ++i) {
        u16 h, l;
        split1(xa[kt][i], h, l); xh[i] = (short)h; xl[i] = (short)l;
        split1(xb[kt][i], h, l); xh[4 + i] = (short)h; xl[4 + i] = (short)l;
      }
      acc = __builtin_amdgcn_mfma_f32_16x16x32_bf16(xh, wih[kt], acc, 0, 0, 0);
      acc = __builtin_amdgcn_mfma_f32_16x16x32_bf16(xl, wih[kt], acc, 0, 0, 0);
      acc = __builtin_amdgcn_mfma_f32_16x16x32_bf16(xh, wil[kt], acc, 0, 0, 0);
    }

    // ---- spill pre-activations to LDS (D layout: col=lane&15, row=(lane>>4)*4+r) ----
    {
      int drow = mbase + ((lane >> 4) << 2);
#pragma unroll
      for (int r = 0; r < 4; ++r) gatesLds[(drow + r) * 17 + colq] = acc[r];
    }
    __syncthreads();

    // ---- elementwise gate math; thread owns one (b,u) ----
    {
      int b = tid >> 2, u = tid & 3;
      const float* gl = &gatesLds[b * 17];
      float xr = gl[u]      + biasSum[u];
      float xf = gl[4 + u]  + biasSum[4 + u];
      float xg = gl[8 + u]  + biasSum[8 + u];
      float xo = gl[12 + u] + biasSum[12 + u];
      float rg = fsigm(xr), fg = fsigm(xf), gg = ftanh(xg), og = fsigm(xo);
      cst = fg * cst + rg * gg;
      float hv = og * ftanh(cst);
      u16 hhi, hlo; split1(hv, hhi, hlo);
      int hidx = b * NH + wg * 4 + u;
      u32 packed = (u32)hhi | ((u32)hlo << 16);
      // device-scope atomic store -> coherent point (readable by all XCDs)
      __hip_atomic_store(&hbuf[(size_t)(t & 1) * (NB * NH) + hidx], packed,
                         __ATOMIC_RELAXED, __HIP_MEMORY_SCOPE_AGENT);
      hs_all[(size_t)(t - 1) * (NB * NH) + hidx] = hhi;
      if (t == NT) hlast[hidx] = hv;
    }

    // ---- publish: drain stores device-wide, then raise our flag (release) ----
    __threadfence();
    __syncthreads();
    if (tid == 0)
      __hip_atomic_store(&flags[wg * FS], t, __ATOMIC_RELEASE, __HIP_MEMORY_SCOPE_AGENT);
  }
}

// ---------------- attention + output head (one WG per batch) ----------------
__global__ __launch_bounds__(256) void post_kernel(
    const float* __restrict__ hlast,  // [B][H] fp32
    const u16* __restrict__ hs,       // [T][B][H] bf16
    const float* __restrict__ W_ol, const float* __restrict__ b_ol,   // [256][512], [256]
    const float* __restrict__ W_att, const float* __restrict__ b_att, // [256][512], [512]
    const float* __restrict__ W_fc, const float* __restrict__ b_fc,   // [2][768], [2]
    float* __restrict__ out)          // [64*2] ++ [64*512] fp32
{
  int b = blockIdx.x, tid = threadIdx.x;
  __shared__ float hl[NH], fh[256], sc[NH], att[NT], ao[NH], red[256];

  for (int i = tid; i < NH; i += 256) {
    float hv = hlast[b * NH + i];
    hl[i] = hv;
    out[128 + b * NH + i] = hv;   // output 1: h_last
  }
  __syncthreads();

  // final_hidden[j] = b_ol[j] + hl . W_ol[j][:]
  {
    float s = b_ol[tid];
    const float* w = W_ol + (size_t)tid * NH;
    for (int k = 0; k < NH; k += 4) {
      f32x4 q = *(const f32x4*)(w + k);
      s += q[0] * hl[k] + q[1] * hl[k + 1] + q[2] * hl[k + 2] + q[3] * hl[k + 3];
    }
    fh[tid] = s;
  }
  __syncthreads();

  // score[h] = b_att[h] + sum_j fh[j] * W_att[j][h]
  for (int h = tid; h < NH; h += 256) {
    float s = b_att[h];
    for (int j = 0; j < 256; ++j) s += fh[j] * W_att[(size_t)j * NH + h];
    sc[h] = s;
  }
  __syncthreads();

  // att[t] = score . hs[t][b][:]
  for (int t = tid; t < NT; t += 256) {
    const u16* row = hs + ((size_t)t * NB + b) * NH;
    float s = 0.f;
    for (int k = 0; k < NH; k += 8) {
      uint4 q = *(const uint4*)(row + k);
      float tmp[8]; unpack8(q, tmp);
#pragma unroll
      for (int j = 0; j < 8; ++j) s += tmp[j] * sc[k + j];
    }
    att[t] = s;
  }
  __syncthreads();

  // softmax over T
  float l0 = att[tid], l1 = att[tid + 256];
  red[tid] = fmaxf(l0, l1);
  __syncthreads();
  for (int s = 128; s > 0; s >>= 1) { if (tid < s) red[tid] = fmaxf(red[tid], red[tid + s]); __syncthreads(); }
  float mx = red[0];
  __syncthreads();
  float e0 = __expf(l0 - mx), e1 = __expf(l1 - mx);
  red[tid] = e0 + e1;
  __syncthreads();
  for (int s = 128; s > 0; s >>= 1) { if (tid < s) red[tid] += red[tid + s]; __syncthreads(); }
  float inv = 1.0f / red[0];
  __syncthreads();
  att[tid] = e0 * inv;
  att[tid + 256] = e1 * inv;
  __syncthreads();

  // att_out[h] = sum_t dist[t] * hs[t][b][h]
  {
    float a0 = 0.f, a1 = 0.f;
    for (int t = 0; t < NT; ++t) {
      float d = att[t];
      const u16* row = hs + ((size_t)t * NB + b) * NH;
      a0 += d * bf2f(row[tid]);
      a1 += d * bf2f(row[tid + 256]);
    }
    ao[tid] = a0;
    ao[tid + 256] = a1;
  }
  __syncthreads();

  // out[o] = sigmoid(b_fc[o] + [fh, ao] . W_fc[o][:])
#pragma unroll
  for (int o = 0; o < 2; ++o) {
    float part = 0.f;
    for (int i = tid; i < 768; i += 256) {
      float v = (i < 256) ? fh[i] : ao[i - 256];
      part += v * W_fc[o * 768 + i];
    }
    red[tid] = part;
    __syncthreads();
    for (int s = 128; s > 0; s >>= 1) { if (tid < s) red[tid] += red[tid + s]; __syncthreads(); }
    if (tid == 0) out[b * 2 + o] = fsigm(red[0] + b_fc[o]);
    __syncthreads();
  }
}

// ---------------- host launch ----------------
extern "C" void kernel_launch(void* const* d_in, const int* in_sizes, int n_in,
                              void* d_out, int out_size, void* d_ws, size_t ws_size,
                              hipStream_t stream) {
  const int* words  = (const int*)d_in[0];
  const float* emb  = (const float*)d_in[1];
  const float* Wir  = (const float*)d_in[2];  const float* bir = (const float*)d_in[3];
  const float* Whr  = (const float*)d_in[4];  const float* bhr = (const float*)d_in[5];
  const float* Wif  = (const float*)d_in[6];  const float* bif = (const float*)d_in[7];
  const float* Whf  = (const float*)d_in[8];  const float* bhf = (const float*)d_in[9];
  const float* Wig  = (const float*)d_in[10]; const float* big_ = (const float*)d_in[11];
  const float* Whg  = (const float*)d_in[12]; const float* bhg = (const float*)d_in[13];
  const float* Wio  = (const float*)d_in[14]; const float* bio = (const float*)d_in[15];
  const float* Who  = (const float*)d_in[16]; const float* bho = (const float*)d_in[17];
  const float* W_att = (const float*)d_in[18]; const float* b_att = (const float*)d_in[19];
  const float* W_ol  = (const float*)d_in[20]; const float* b_ol  = (const float*)d_in[21];
  const float* W_fc  = (const float*)d_in[22]; const float* b_fc  = (const float*)d_in[23];

  uint8_t* ws = (uint8_t*)d_ws;
  u16* hs       = (u16*)ws;                            // 512*64*512*2 = 32 MiB
  size_t off    = (size_t)33554432;
  u32* hbuf     = (u32*)(ws + off);  off += 262144;    // 2*64*512*4 packed hi|lo
  float* hlast  = (float*)(ws + off); off += 131072;   // 64*512*4
  int* flags    = (int*)(ws + off);                    // 128*16*4 = 8 KiB

  hipMemsetAsync(flags, 0, NWG * FS * sizeof(int), stream);

  // REGULAR launch (not cooperative): 128 blocks <= 256 CUs guarantees
  // co-residency; cooperative launch fails silently in this harness.
  lstm_persistent<<<dim3(NWG), dim3(256), 0, stream>>>(
      words, emb,
      Whr, Whf, Whg, Who,
      Wir, Wif, Wig, Wio,
      bhr, bhf, bhg, bho,
      bir, bif, big_, bio,
      hbuf, hs, hlast, flags);

  post_kernel<<<dim3(NB), dim3(256), 0, stream>>>(hlast, hs, W_ol, b_ol, W_att, b_att,
                                                  W_fc, b_fc, (float*)d_out);
}

// Round 6
// 7297.355 us; speedup vs baseline: 2.4674x; 2.4674x over previous
//
#include <hip/hip_runtime.h>
#include <cstdint>
#include <cstddef>

typedef unsigned short u16;
typedef unsigned int u32;
typedef unsigned long long u64;
typedef __attribute__((ext_vector_type(8))) short bfrag8;   // 8 bf16 = 4 VGPRs
typedef __attribute__((ext_vector_type(4))) float f32x4;

#define NB 64      // batch
#define NT 512     // timesteps
#define NE 256     // embedding dim
#define NH 512     // hidden dim
#define NWG 128    // persistent workgroups (4 units x 4 gates = 16 cols each)
#define FS 16      // flag stride in ints (64 B apart)

__device__ __forceinline__ float bf2f(u16 b) { return __uint_as_float(((unsigned)b) << 16); }
__device__ __forceinline__ u16 f2bf(float f) {
  unsigned u = __float_as_uint(f);
  u += 0x7fffu + ((u >> 16) & 1u);   // round-to-nearest-even
  return (u16)(u >> 16);
}
__device__ __forceinline__ float fsigm(float x) { return 1.0f / (1.0f + __expf(-x)); }
__device__ __forceinline__ float ftanh(float x) { return 2.0f / (1.0f + __expf(-2.0f * x)) - 1.0f; }

// split fp32 -> (hi, lo) bf16 pair; hi + lo == v to ~2^-18 relative
__device__ __forceinline__ void split1(float v, u16& h, u16& l) {
  h = f2bf(v);
  float r = v - bf2f(h);
  l = f2bf(r);
}
__device__ __forceinline__ void split8(const float* p, bfrag8& hi, bfrag8& lo) {
#pragma unroll
  for (int i = 0; i < 8; ++i) {
    u16 h, l; split1(p[i], h, l);
    hi[i] = (short)h; lo[i] = (short)l;
  }
}

__device__ __forceinline__ void unpack8(uint4 q, float* o) {
  o[0] = __uint_as_float(q.x << 16); o[1] = __uint_as_float(q.x & 0xffff0000u);
  o[2] = __uint_as_float(q.y << 16); o[3] = __uint_as_float(q.y & 0xffff0000u);
  o[4] = __uint_as_float(q.z << 16); o[5] = __uint_as_float(q.z & 0xffff0000u);
  o[6] = __uint_as_float(q.w << 16); o[7] = __uint_as_float(q.w & 0xffff0000u);
}

// ---------------- persistent LSTM recurrence (fp32-accurate via split-bf16 MFMA) ----
// WG g owns hidden units [g*4, g*4+4) x 4 gates (16 output cols), all 64 batches.
// col c in [0,16): gate = c>>2 (0=r,1=f,2=g,3=o), unit = g*4 + (c&3).
// wave w handles batch tile [w*16, w*16+16).
// REGULAR launch: 128 blocks <= 256 CUs -> co-resident even at 1 wave/SIMD.
// Exchange protocol (proven in R5, latency-optimized here):
//   producer: agent-scope write-through atomic h store -> __syncthreads()
//             (s_waitcnt vmcnt(0)+s_barrier drains all stores to coherence pt)
//             -> tid0 RELEASE flag store.
//   consumer: relaxed flag poll -> ACQUIRE agent fence (buffer_inv)
//             -> plain vectorized h loads (fetch from coherence point).
__global__ __launch_bounds__(256, 1) void lstm_persistent(
    const int* __restrict__ words,
    const float* __restrict__ emb,
    const float* __restrict__ Whr, const float* __restrict__ Whf,
    const float* __restrict__ Whg, const float* __restrict__ Who,
    const float* __restrict__ Wir, const float* __restrict__ Wif,
    const float* __restrict__ Wig, const float* __restrict__ Wio,
    const float* __restrict__ bhr, const float* __restrict__ bhf,
    const float* __restrict__ bhg, const float* __restrict__ bho,
    const float* __restrict__ bir, const float* __restrict__ bif,
    const float* __restrict__ big_, const float* __restrict__ bio,
    u32* __restrict__ hbuf,     // [2][B][H] packed bf16 hi | lo<<16
    u16* __restrict__ hs_all,   // [T][B][H] bf16 (attention path)
    float* __restrict__ hlast,  // [B][H] fp32 final h
    int* __restrict__ flags)    // [NWG*FS]
{
  const int wg = blockIdx.x;
  const int tid = threadIdx.x;
  const int lane = tid & 63;
  const int wave = tid >> 6;
  const int mbase = wave * 16;
  const int colq = lane & 15;
  const int koff = (lane >> 4) * 8;
  const int arow = mbase + colq;            // batch row for A fragments

  __shared__ float gatesLds[NB * 17];       // [b][col], stride 17
  __shared__ float biasSum[16];

  if (tid < 16) {
    int gate = tid >> 2, u = tid & 3, gu = wg * 4 + u;
    const float* bh = (gate == 0) ? bhr : (gate == 1) ? bhf : (gate == 2) ? bhg : bho;
    const float* bi = (gate == 0) ? bir : (gate == 1) ? bif : (gate == 2) ? big_ : bio;
    biasSum[tid] = bh[gu] + bi[gu];
  }

  // ---- persistent weight fragments (hi/lo split), B-layout:
  // lane L holds B[k=(L>>4)*8+j][col=L&15]
  bfrag8 whh[16], whl[16], wih[8], wil[8];
  {
    int gate = colq >> 2;
    int gu = wg * 4 + (colq & 3);
    const float* wh = (gate == 0) ? Whr : (gate == 1) ? Whf : (gate == 2) ? Whg : Who;
    const float* wi = (gate == 0) ? Wir : (gate == 1) ? Wif : (gate == 2) ? Wig : Wio;
    const float* whp = wh + (size_t)gu * NH + koff;
    const float* wip = wi + (size_t)gu * NE + koff;
#pragma unroll
    for (int kt = 0; kt < 16; ++kt) split8(whp + kt * 32, whh[kt], whl[kt]);
#pragma unroll
    for (int kt = 0; kt < 8; ++kt)  split8(wip + kt * 32, wih[kt], wil[kt]);
  }
  __syncthreads();

  // int64-vs-int32 hedge for word indices
  bool is64 = ((words[1] | words[3] | words[5] | words[7]) == 0);
  const int wstep = is64 ? 2 : 1;
  const int* wrow = words + (size_t)(is64 ? 2 : 1) * arow * NT;

  float cst = 0.0f;   // fp32 cell state for (b = tid>>2, u = tid&3)

  // ---- X pipeline: prologue loads + split for t=1 ----
  f32x4 nxa[8], nxb[8];        // raw fp32 emb for NEXT step (prefetch)
  bfrag8 xh[8], xl[8];         // split fragments for CURRENT step
  {
    int w0 = wrow[0];
    const float* xs = emb + (size_t)w0 * NE + koff;
#pragma unroll
    for (int kt = 0; kt < 8; ++kt) {
      nxa[kt] = *(const f32x4*)(xs + kt * 32);
      nxb[kt] = *(const f32x4*)(xs + kt * 32 + 4);
    }
#pragma unroll
    for (int kt = 0; kt < 8; ++kt) {
#pragma unroll
      for (int i = 0; i < 4; ++i) {
        u16 h, l;
        split1(nxa[kt][i], h, l); xh[kt][i] = (short)h; xl[kt][i] = (short)l;
        split1(nxb[kt][i], h, l); xh[kt][4 + i] = (short)h; xl[kt][4 + i] = (short)l;
      }
    }
  }

  for (int t = 1; t <= NT; ++t) {
    // ---- prefetch X for t+1 (latency hides under poll wait) ----
    if (t < NT) {
      int wn = wrow[(size_t)t * wstep];
      const float* xs = emb + (size_t)wn * NE + koff;
#pragma unroll
      for (int kt = 0; kt < 8; ++kt) {
        nxa[kt] = *(const f32x4*)(xs + kt * 32);
        nxb[kt] = *(const f32x4*)(xs + kt * 32 + 4);
      }
    }

    // ---- X MFMAs (independent of h_{t-1}) ----
    f32x4 acc = {0.f, 0.f, 0.f, 0.f};
#pragma unroll
    for (int kt = 0; kt < 8; ++kt) {
      acc = __builtin_amdgcn_mfma_f32_16x16x32_bf16(xh[kt], wih[kt], acc, 0, 0, 0);
      acc = __builtin_amdgcn_mfma_f32_16x16x32_bf16(xl[kt], wih[kt], acc, 0, 0, 0);
      acc = __builtin_amdgcn_mfma_f32_16x16x32_bf16(xh[kt], wil[kt], acc, 0, 0, 0);
    }

    if (t > 1) {
      // ---- wait for all 128 WGs to publish h_{t-1} ----
      const int need = t - 1;
      int f0, f1;
      do {
        f0 = __hip_atomic_load(&flags[lane * FS], __ATOMIC_RELAXED, __HIP_MEMORY_SCOPE_AGENT);
        f1 = __hip_atomic_load(&flags[(lane + 64) * FS], __ATOMIC_RELAXED, __HIP_MEMORY_SCOPE_AGENT);
      } while (__all(f0 >= need && f1 >= need) == 0);
      // acquire: invalidate L1/L2 so plain loads fetch from coherence point
      __builtin_amdgcn_fence(__ATOMIC_ACQUIRE, "agent");

      // ---- h loads: plain pipelined dwordx4 of packed hi|lo u32 ----
      const u32* hp = hbuf + ((size_t)((t - 1) & 1) * NB + arow) * NH + koff;
      uint4 hq0[16], hq1[16];
#pragma unroll
      for (int kt = 0; kt < 16; ++kt) {
        hq0[kt] = *(const uint4*)(hp + kt * 32);
        hq1[kt] = *(const uint4*)(hp + kt * 32 + 4);
      }
#pragma unroll
      for (int kt = 0; kt < 16; ++kt) {
        bfrag8 ah, al;
        uint4 q0 = hq0[kt], q1 = hq1[kt];
        ah[0] = (short)(q0.x & 0xffffu); al[0] = (short)(q0.x >> 16);
        ah[1] = (short)(q0.y & 0xffffu); al[1] = (short)(q0.y >> 16);
        ah[2] = (short)(q0.z & 0xffffu); al[2] = (short)(q0.z >> 16);
        ah[3] = (short)(q0.w & 0xffffu); al[3] = (short)(q0.w >> 16);
        ah[4] = (short)(q1.x & 0xffffu); al[4] = (short)(q1.x >> 16);
        ah[5] = (short)(q1.y & 0xffffu); al[5] = (short)(q1.y >> 16);
        ah[6] = (short)(q1.z & 0xffffu); al[6] = (short)(q1.z >> 16);
        ah[7] = (short)(q1.w & 0xffffu); al[7] = (short)(q1.w >> 16);
        acc = __builtin_amdgcn_mfma_f32_16x16x32_bf16(ah, whh[kt], acc, 0, 0, 0);
        acc = __builtin_amdgcn_mfma_f32_16x16x32_bf16(al, whh[kt], acc, 0, 0, 0);
        acc = __builtin_amdgcn_mfma_f32_16x16x32_bf16(ah, whl[kt], acc, 0, 0, 0);
      }
    }

    // ---- spill pre-activations to LDS (D layout: col=lane&15, row=(lane>>4)*4+r) ----
    {
      int drow = mbase + ((lane >> 4) << 2);
#pragma unroll
      for (int r = 0; r < 4; ++r) gatesLds[(drow + r) * 17 + colq] = acc[r];
    }
    __syncthreads();

    // ---- elementwise gate math; thread owns one (b,u) ----
    {
      int b = tid >> 2, u = tid & 3;
      const float* gl = &gatesLds[b * 17];
      float xr = gl[u]      + biasSum[u];
      float xf = gl[4 + u]  + biasSum[4 + u];
      float xg = gl[8 + u]  + biasSum[8 + u];
      float xo = gl[12 + u] + biasSum[12 + u];
      float rg = fsigm(xr), fg = fsigm(xf), gg = ftanh(xg), og = fsigm(xo);
      cst = fg * cst + rg * gg;
      float hv = og * ftanh(cst);
      u16 hhi, hlo; split1(hv, hhi, hlo);
      int hidx = b * NH + wg * 4 + u;
      u32 packed = (u32)hhi | ((u32)hlo << 16);
      // agent-scope write-through store -> coherence point
      __hip_atomic_store(&hbuf[(size_t)(t & 1) * (NB * NH) + hidx], packed,
                         __ATOMIC_RELAXED, __HIP_MEMORY_SCOPE_AGENT);
      hs_all[(size_t)(t - 1) * (NB * NH) + hidx] = hhi;
      if (t == NT) hlast[hidx] = hv;
    }

    // ---- publish: barrier drains all threads' stores (s_waitcnt vmcnt(0)),
    //      then single release flag store ----
    __syncthreads();
    if (tid == 0)
      __hip_atomic_store(&flags[wg * FS], t, __ATOMIC_RELEASE, __HIP_MEMORY_SCOPE_AGENT);

    // ---- split prefetched X(t+1) -> current fragments (off critical path) ----
    if (t < NT) {
#pragma unroll
      for (int kt = 0; kt < 8; ++kt) {
#pragma unroll
        for (int i = 0; i < 4; ++i) {
          u16 h, l;
          split1(nxa[kt][i], h, l); xh[kt][i] = (short)h; xl[kt][i] = (short)l;
          split1(nxb[kt][i], h, l); xh[kt][4 + i] = (short)h; xl[kt][4 + i] = (short)l;
        }
      }
    }
  }
}

// ---------------- attention + output head (one WG per batch) ----------------
__global__ __launch_bounds__(256) void post_kernel(
    const float* __restrict__ hlast,  // [B][H] fp32
    const u16* __restrict__ hs,       // [T][B][H] bf16
    const float* __restrict__ W_ol, const float* __restrict__ b_ol,   // [256][512], [256]
    const float* __restrict__ W_att, const float* __restrict__ b_att, // [256][512], [512]
    const float* __restrict__ W_fc, const float* __restrict__ b_fc,   // [2][768], [2]
    float* __restrict__ out)          // [64*2] ++ [64*512] fp32
{
  int b = blockIdx.x, tid = threadIdx.x;
  __shared__ float hl[NH], fh[256], sc[NH], att[NT], ao[NH], red[256];

  for (int i = tid; i < NH; i += 256) {
    float hv = hlast[b * NH + i];
    hl[i] = hv;
    out[128 + b * NH + i] = hv;   // output 1: h_last
  }
  __syncthreads();

  // final_hidden[j] = b_ol[j] + hl . W_ol[j][:]
  {
    float s = b_ol[tid];
    const float* w = W_ol + (size_t)tid * NH;
    for (int k = 0; k < NH; k += 4) {
      f32x4 q = *(const f32x4*)(w + k);
      s += q[0] * hl[k] + q[1] * hl[k + 1] + q[2] * hl[k + 2] + q[3] * hl[k + 3];
    }
    fh[tid] = s;
  }
  __syncthreads();

  // score[h] = b_att[h] + sum_j fh[j] * W_att[j][h]
  for (int h = tid; h < NH; h += 256) {
    float s = b_att[h];
    for (int j = 0; j < 256; ++j) s += fh[j] * W_att[(size_t)j * NH + h];
    sc[h] = s;
  }
  __syncthreads();

  // att[t] = score . hs[t][b][:]
  for (int t = tid; t < NT; t += 256) {
    const u16* row = hs + ((size_t)t * NB + b) * NH;
    float s = 0.f;
    for (int k = 0; k < NH; k += 8) {
      uint4 q = *(const uint4*)(row + k);
      float tmp[8]; unpack8(q, tmp);
#pragma unroll
      for (int j = 0; j < 8; ++j) s += tmp[j] * sc[k + j];
    }
    att[t] = s;
  }
  __syncthreads();

  // softmax over T
  float l0 = att[tid], l1 = att[tid + 256];
  red[tid] = fmaxf(l0, l1);
  __syncthreads();
  for (int s = 128; s > 0; s >>= 1) { if (tid < s) red[tid] = fmaxf(red[tid], red[tid + s]); __syncthreads(); }
  float mx = red[0];
  __syncthreads();
  float e0 = __expf(l0 - mx), e1 = __expf(l1 - mx);
  red[tid] = e0 + e1;
  __syncthreads();
  for (int s = 128; s > 0; s >>= 1) { if (tid < s) red[tid] += red[tid + s]; __syncthreads(); }
  float inv = 1.0f / red[0];
  __syncthreads();
  att[tid] = e0 * inv;
  att[tid + 256] = e1 * inv;
  __syncthreads();

  // att_out[h] = sum_t dist[t] * hs[t][b][h]
  {
    float a0 = 0.f, a1 = 0.f;
    for (int t = 0; t < NT; ++t) {
      float d = att[t];
      const u16* row = hs + ((size_t)t * NB + b) * NH;
      a0 += d * bf2f(row[tid]);
      a1 += d * bf2f(row[tid + 256]);
    }
    ao[tid] = a0;
    ao[tid + 256] = a1;
  }
  __syncthreads();

  // out[o] = sigmoid(b_fc[o] + [fh, ao] . W_fc[o][:])
#pragma unroll
  for (int o = 0; o < 2; ++o) {
    float part = 0.f;
    for (int i = tid; i < 768; i += 256) {
      float v = (i < 256) ? fh[i] : ao[i - 256];
      part += v * W_fc[o * 768 + i];
    }
    red[tid] = part;
    __syncthreads();
    for (int s = 128; s > 0; s >>= 1) { if (tid < s) red[tid] += red[tid + s]; __syncthreads(); }
    if (tid == 0) out[b * 2 + o] = fsigm(red[0] + b_fc[o]);
    __syncthreads();
  }
}

// ---------------- host launch ----------------
extern "C" void kernel_launch(void* const* d_in, const int* in_sizes, int n_in,
                              void* d_out, int out_size, void* d_ws, size_t ws_size,
                              hipStream_t stream) {
  const int* words  = (const int*)d_in[0];
  const float* emb  = (const float*)d_in[1];
  const float* Wir  = (const float*)d_in[2];  const float* bir = (const float*)d_in[3];
  const float* Whr  = (const float*)d_in[4];  const float* bhr = (const float*)d_in[5];
  const float* Wif  = (const float*)d_in[6];  const float* bif = (const float*)d_in[7];
  const float* Whf  = (const float*)d_in[8];  const float* bhf = (const float*)d_in[9];
  const float* Wig  = (const float*)d_in[10]; const float* big_ = (const float*)d_in[11];
  const float* Whg  = (const float*)d_in[12]; const float* bhg = (const float*)d_in[13];
  const float* Wio  = (const float*)d_in[14]; const float* bio = (const float*)d_in[15];
  const float* Who  = (const float*)d_in[16]; const float* bho = (const float*)d_in[17];
  const float* W_att = (const float*)d_in[18]; const float* b_att = (const float*)d_in[19];
  const float* W_ol  = (const float*)d_in[20]; const float* b_ol  = (const float*)d_in[21];
  const float* W_fc  = (const float*)d_in[22]; const float* b_fc  = (const float*)d_in[23];

  uint8_t* ws = (uint8_t*)d_ws;
  u16* hs       = (u16*)ws;                            // 512*64*512*2 = 32 MiB
  size_t off    = (size_t)33554432;
  u32* hbuf     = (u32*)(ws + off);  off += 262144;    // 2*64*512*4 packed hi|lo
  float* hlast  = (float*)(ws + off); off += 131072;   // 64*512*4
  int* flags    = (int*)(ws + off);                    // 128*16*4 = 8 KiB

  hipMemsetAsync(flags, 0, NWG * FS * sizeof(int), stream);

  lstm_persistent<<<dim3(NWG), dim3(256), 0, stream>>>(
      words, emb,
      Whr, Whf, Whg, Who,
      Wir, Wif, Wig, Wio,
      bhr, bhf, bhg, bho,
      bir, bif, big_, bio,
      hbuf, hs, hlast, flags);

  post_kernel<<<dim3(NB), dim3(256), 0, stream>>>(hlast, hs, W_ol, b_ol, W_att, b_att,
                                                  W_fc, b_fc, (float*)d_out);
}